// Round 5
// baseline (1143.598 us; speedup 1.0000x reference)
//
#include <hip/hip_runtime.h>
#include <hip/hip_bf16.h>

// Problem constants (fixed shapes)
#define NN 2048      // nodes
#define EE 65536     // edges
#define NF_ 128
#define HH 512
#define NHH 8
#define HD 64
#define DEPTH 5
#define KSPLIT 2
#define KEYS_PER (NN / KSPLIT)   // 1024
#define NTILE (KEYS_PER / 64)    // 16

typedef __attribute__((ext_vector_type(8))) short bf16x8;
typedef __attribute__((ext_vector_type(4))) float f32x4;

__device__ __forceinline__ ushort f2bf(float x) {
    uint u = __builtin_bit_cast(uint, x);
    u += 0x7fffu + ((u >> 16) & 1u);
    return (ushort)(u >> 16);
}

#define GLD16(gp, lp)                                                          \
    __builtin_amdgcn_global_load_lds(                                          \
        (const __attribute__((address_space(1))) unsigned int*)(gp),           \
        (__attribute__((address_space(3))) unsigned int*)(lp), 16, 0, 0)

// raw barrier: LDS visible, vmem loads stay in flight
__device__ __forceinline__ void bar_lgkm() {
    asm volatile("s_waitcnt lgkmcnt(0)" ::: "memory");
    __builtin_amdgcn_s_barrier();
    __builtin_amdgcn_sched_barrier(0);
}
// barrier that additionally waits V-stage (2 newest loads = prefetched K allowed in flight)
__device__ __forceinline__ void bar_vm(int pk) {
    if (pk) asm volatile("s_waitcnt vmcnt(2) lgkmcnt(0)" ::: "memory");
    else    asm volatile("s_waitcnt vmcnt(0) lgkmcnt(0)" ::: "memory");
    __builtin_amdgcn_s_barrier();
    __builtin_amdgcn_sched_barrier(0);
}

// ---------------- bf16 MFMA GEMM: C = A[M,K] @ Bt[N,K]^T + bias
// OUT: 0 = f32 C; 1 = f32 C + bf16 Cb; 2 = bf16 Cb; 3 = qkv scatter (q/k head-major, v transposed)
template<int BN, int OUT, int RELU>
__global__ __launch_bounds__(256) void gemm_mfma(const ushort* __restrict__ A,
                                                 const ushort* __restrict__ Bt,
                                                 const float* __restrict__ bias,
                                                 float* __restrict__ C,
                                                 ushort* __restrict__ Cb,
                                                 ushort* __restrict__ qb,
                                                 ushort* __restrict__ kb,
                                                 ushort* __restrict__ vtb,
                                                 int M, int N, int K) {
    constexpr int WN = BN / 2;
    constexpr int NR = WN / 16;
    __shared__ __align__(16) ushort As[2][128 * 64];
    __shared__ __align__(16) ushort Bs[2][BN * 64];
    const int t = threadIdx.x;
    const int w = t >> 6, l = t & 63;
    const int wr = w >> 1, wc = w & 1;
    const int m0 = blockIdx.y * 128, n0 = blockIdx.x * BN;

    f32x4 acc[4][NR];
#pragma unroll
    for (int m = 0; m < 4; ++m)
#pragma unroll
        for (int n = 0; n < NR; ++n) acc[m][n] = (f32x4){0.f, 0.f, 0.f, 0.f};

    const int srow = t >> 3, sch = t & 7;
    auto stage = [&](int buf, int kt) {
#pragma unroll
        for (int r = 0; r < 4; ++r) {
            int rr = r * 32 + srow;
            int c = sch ^ (rr & 7);                   // inverse swizzle on SOURCE
            GLD16(A + (size_t)(m0 + rr) * K + kt * 64 + c * 8,
                  &As[buf][rr * 64 + sch * 8]);       // linear LDS dest
        }
#pragma unroll
        for (int r = 0; r < BN / 32; ++r) {
            int rr = r * 32 + srow;
            int c = sch ^ (rr & 7);
            GLD16(Bt + (size_t)(n0 + rr) * K + kt * 64 + c * 8,
                  &Bs[buf][rr * 64 + sch * 8]);
        }
    };

    stage(0, 0);
    const int NT = K / 64;
    for (int kt = 0; kt < NT; ++kt) {
        __syncthreads();
        if (kt + 1 < NT) stage((kt + 1) & 1, kt + 1);
        const int buf = kt & 1;
#pragma unroll
        for (int kk = 0; kk < 2; ++kk) {
            bf16x8 af[4], bfr[NR];
#pragma unroll
            for (int m = 0; m < 4; ++m) {
                int R = wr * 64 + m * 16 + (l & 15);
                int c = kk * 4 + (l >> 4);
                af[m] = *(const bf16x8*)&As[buf][R * 64 + (c ^ (R & 7)) * 8];
            }
#pragma unroll
            for (int n = 0; n < NR; ++n) {
                int R = wc * WN + n * 16 + (l & 15);
                int c = kk * 4 + (l >> 4);
                bfr[n] = *(const bf16x8*)&Bs[buf][R * 64 + (c ^ (R & 7)) * 8];
            }
#pragma unroll
            for (int m = 0; m < 4; ++m)
#pragma unroll
                for (int n = 0; n < NR; ++n)
                    acc[m][n] = __builtin_amdgcn_mfma_f32_16x16x32_bf16(af[m], bfr[n], acc[m][n], 0, 0, 0);
        }
    }

#pragma unroll
    for (int m = 0; m < 4; ++m) {
        int row = m0 + wr * 64 + m * 16 + (l >> 4) * 4;
#pragma unroll
        for (int n = 0; n < NR; ++n) {
            int col = n0 + wc * WN + n * 16 + (l & 15);
            float bv = bias[col];
#pragma unroll
            for (int j = 0; j < 4; ++j) {
                float vv = acc[m][n][j] + bv;
                if (RELU) vv = fmaxf(vv, 0.f);
                int r = row + j;
                if (OUT == 0) {
                    C[(size_t)r * N + col] = vv;
                } else if (OUT == 1) {
                    C[(size_t)r * N + col] = vv;
                    Cb[(size_t)r * N + col] = f2bf(vv);
                } else if (OUT == 2) {
                    Cb[(size_t)r * N + col] = f2bf(vv);
                } else {
                    int type = col >> 9, head = (col >> 6) & 7, dd = col & 63;
                    ushort bv16 = f2bf(vv);
                    if (type == 0) qb[((size_t)head * NN + r) * 64 + dd] = bv16;
                    else if (type == 1) kb[((size_t)head * NN + r) * 64 + dd] = bv16;
                    else vtb[((size_t)head * 64 + dd) * NN + r] = bv16;
                }
            }
        }
    }
}

// ---------------- setup converts
__global__ __launch_bounds__(256) void xcvt(const float* __restrict__ x, ushort* __restrict__ xb, int n) {
    int i = blockIdx.x * 256 + threadIdx.x;
    if (i < n) xb[i] = f2bf(x[i]);
}

__global__ __launch_bounds__(256) void wtrans(const float* __restrict__ W, ushort* __restrict__ WT,
                                              int K, int N, int rowoff) {
    __shared__ float tile[32][33];
    int n0 = blockIdx.x * 32, k0 = blockIdx.y * 32;
    int tc = threadIdx.x & 31, tr = threadIdx.x >> 5;
#pragma unroll
    for (int i = 0; i < 32; i += 8) tile[tr + i][tc] = W[(size_t)(k0 + tr + i) * N + n0 + tc];
    __syncthreads();
#pragma unroll
    for (int i = 0; i < 32; i += 8)
        WT[(size_t)(rowoff + n0 + tr + i) * K + k0 + tc] = f2bf(tile[tc][tr + i]);
}

__global__ __launch_bounds__(256) void bconcat(const float* __restrict__ a, const float* __restrict__ b,
                                               const float* __restrict__ c, float* __restrict__ o) {
    int i = blockIdx.x * 256 + threadIdx.x;
    if (i < 1536) o[i] = i < 512 ? a[i] : (i < 1024 ? b[i - 512] : c[i - 1024]);
}

// ---------------- e_bias = edge_attr @ We + be
__global__ __launch_bounds__(256) void ebias_kernel(const float* __restrict__ ea,
                                                    const float* __restrict__ We,
                                                    const float* __restrict__ be,
                                                    float* __restrict__ eb) {
    int e = blockIdx.x * 256 + threadIdx.x;
    float a[16];
#pragma unroll
    for (int i = 0; i < 16; ++i) a[i] = ea[(size_t)e * 16 + i];
#pragma unroll
    for (int j = 0; j < 8; ++j) {
        float s = be[j];
#pragma unroll
        for (int i = 0; i < 16; ++i) s += a[i] * We[i * 8 + j];
        eb[(size_t)e * 8 + j] = s;
    }
}

// ---------------- dedupe: last edge index wins per (src,dst)
__global__ __launch_bounds__(256) void amax_kernel(const int* __restrict__ eidx, int* __restrict__ lastE) {
    int e = blockIdx.x * 256 + threadIdx.x;
    int s = eidx[e], d = eidx[EE + e];
    atomicMax(&lastE[s * NN + d], e);
}

__global__ __launch_bounds__(256) void count_kernel(const int* __restrict__ eidx,
                                                    const int* __restrict__ lastE,
                                                    int* __restrict__ cnt) {
    int e = blockIdx.x * 256 + threadIdx.x;
    int s = eidx[e], d = eidx[EE + e];
    if (lastE[s * NN + d] == e) atomicAdd(&cnt[s], 1);
}

__global__ __launch_bounds__(256) void scan2048(const int* __restrict__ cnt,
                                                int* __restrict__ rowptr,
                                                int* __restrict__ rowoff) {
    __shared__ int sums[256];
    int t = threadIdx.x;
    int loc[8];
    int s = 0;
#pragma unroll
    for (int i = 0; i < 8; ++i) { loc[i] = s; s += cnt[t * 8 + i]; }
    sums[t] = s;
    __syncthreads();
    for (int off = 1; off < 256; off <<= 1) {
        int v = (t >= off) ? sums[t - off] : 0;
        __syncthreads();
        sums[t] += v;
        __syncthreads();
    }
    int base = (t == 0) ? 0 : sums[t - 1];
#pragma unroll
    for (int i = 0; i < 8; ++i) { rowptr[t * 8 + i] = base + loc[i]; rowoff[t * 8 + i] = base + loc[i]; }
    if (t == 255) rowptr[NN] = sums[255];
}

__global__ __launch_bounds__(256) void fill_kernel(const int* __restrict__ eidx,
                                                   const int* __restrict__ lastE,
                                                   const float* __restrict__ eb,
                                                   int* __restrict__ rowoff,
                                                   int* __restrict__ csr_dst,
                                                   float* __restrict__ csr_b) {
    int e = blockIdx.x * 256 + threadIdx.x;
    int s = eidx[e], d = eidx[EE + e];
    if (lastE[s * NN + d] == e) {
        int pos = atomicAdd(&rowoff[s], 1);
        csr_dst[pos] = d;
#pragma unroll
        for (int j = 0; j < 8; ++j) csr_b[(size_t)pos * 8 + j] = eb[(size_t)e * 8 + j];
    }
}

// ---------------- split-K flash attention with MFMA bf16
// grid (NN/32, NHH, KSPLIT). Per block: 32 q-rows, 1024 keys, 16 tiles of 64.
// 3 barriers/tile; K dbuf + V single-buf staged via global_load_lds (XOR-swizzled both sides).
__global__ __launch_bounds__(256) void attn_mfma(const ushort* __restrict__ qb,
                                                 const ushort* __restrict__ kb,
                                                 const ushort* __restrict__ vtb,
                                                 const int* __restrict__ rowptr,
                                                 const int* __restrict__ csr_dst,
                                                 const float* __restrict__ csr_b,
                                                 float* __restrict__ opart,
                                                 float* __restrict__ Mp,
                                                 float* __restrict__ Sp) {
    const int n0 = blockIdx.x * 32;
    const int head = blockIdx.y;
    const int ks = blockIdx.z;
    const int t = threadIdx.x;
    const int w = t >> 6, l = t & 63;
    const int mh = w & 1, nh = w >> 1;

    __shared__ __align__(16) ushort Ks2[2][64 * 64];   // K dbuf, swizzled
    __shared__ __align__(16) ushort Vs[64 * 64];       // V single buf, swizzled
    __shared__ __align__(16) float  Sl[32][68];
    __shared__ __align__(16) ushort Pb[32][72];
    __shared__ float Mrow[32], Srow[32], Frow[32];

    // persistent Q fragments
    bf16x8 qf0, qf1;
    {
        int r = n0 + mh * 16 + (l & 15);
        const ushort* qp = qb + ((size_t)head * NN + r) * HD + ((l >> 4) * 8);
        qf0 = *(const bf16x8*)qp;
        qf1 = *(const bf16x8*)(qp + 32);
    }
    if (t < 32) { Mrow[t] = -1e30f; Srow[t] = 0.f; }
    // softmax/bias ownership: row brow, cols [bj*8, bj*8+8)
    const int brow = t >> 3, bj = t & 7;
    const int be0 = rowptr[n0 + brow], be1 = rowptr[n0 + brow + 1];
    f32x4 o0 = {0.f, 0.f, 0.f, 0.f}, o1 = {0.f, 0.f, 0.f, 0.f};

    auto stageK = [&](int buf, int tile) {
        int m0k = ks * KEYS_PER + tile * 64;
#pragma unroll
        for (int s = 0; s < 2; ++s) {
            int slot = t + s * 256;
            int rr = slot >> 3, blk = slot & 7, sb = blk ^ (rr & 7);
            GLD16(kb + ((size_t)head * NN + m0k + rr) * 64 + sb * 8,
                  &Ks2[buf][rr * 64 + blk * 8]);
        }
    };
    auto stageV = [&](int tile) {
        int m0k = ks * KEYS_PER + tile * 64;
#pragma unroll
        for (int s = 0; s < 2; ++s) {
            int slot = t + s * 256;
            int rr = slot >> 3, blk = slot & 7, sb = blk ^ (rr & 7);
            GLD16(vtb + ((size_t)head * 64 + rr) * NN + m0k + sb * 8,
                  &Vs[rr * 64 + blk * 8]);
        }
    };

    stageK(0, 0);
    __syncthreads();   // K(0) landed, Mrow init visible

    for (int tt = 0; tt < NTILE; ++tt) {
        const int buf = tt & 1;
        const int m0k = ks * KEYS_PER + tt * 64;
        const int pk = (tt + 1 < NTILE);
        stageV(tt);                       // V for this tile (awaited mid-iter)
        if (pk) stageK(buf ^ 1, tt + 1);  // K prefetch (awaited at end barrier)

        // ---- QK^T from Ks2[buf] (swizzled reads)
        {
            const ushort* Kb_ = &Ks2[buf][0];
            int db = l >> 4;
            int key0 = nh * 32 + (l & 15), key1 = key0 + 16;
            bf16x8 ka0 = *(const bf16x8*)&Kb_[key0 * 64 + ((db ^ (key0 & 7)) * 8)];
            bf16x8 ka1 = *(const bf16x8*)&Kb_[key0 * 64 + (((db + 4) ^ (key0 & 7)) * 8)];
            bf16x8 kb0 = *(const bf16x8*)&Kb_[key1 * 64 + ((db ^ (key1 & 7)) * 8)];
            bf16x8 kb1 = *(const bf16x8*)&Kb_[key1 * 64 + (((db + 4) ^ (key1 & 7)) * 8)];
            f32x4 s0 = {0.f, 0.f, 0.f, 0.f}, s1 = {0.f, 0.f, 0.f, 0.f};
            __builtin_amdgcn_s_setprio(1);
            s0 = __builtin_amdgcn_mfma_f32_16x16x32_bf16(qf0, ka0, s0, 0, 0, 0);
            s0 = __builtin_amdgcn_mfma_f32_16x16x32_bf16(qf1, ka1, s0, 0, 0, 0);
            s1 = __builtin_amdgcn_mfma_f32_16x16x32_bf16(qf0, kb0, s1, 0, 0, 0);
            s1 = __builtin_amdgcn_mfma_f32_16x16x32_bf16(qf1, kb1, s1, 0, 0, 0);
            __builtin_amdgcn_s_setprio(0);
            int row = mh * 16 + (l >> 4) * 4;
            int c0 = nh * 32 + (l & 15);
#pragma unroll
            for (int j = 0; j < 4; ++j) {
                Sl[row + j][c0] = s0[j] * 0.125f;
                Sl[row + j][c0 + 16] = s1[j] * 0.125f;
            }
        }
        bar_lgkm();   // Sl visible; staging loads stay in flight

        // ---- bias (ownership-filtered scan) + online softmax
        {
            const int cbase = bj * 8;
            for (int e = be0; e < be1; ++e) {
                unsigned rel = (unsigned)(csr_dst[e] - m0k - cbase);
                if (rel < 8u) Sl[brow][cbase + rel] += csr_b[(size_t)e * 8 + head];
            }
            f32x4 a = *(const f32x4*)&Sl[brow][cbase];
            f32x4 b = *(const f32x4*)&Sl[brow][cbase + 4];
            float tm = fmaxf(fmaxf(fmaxf(a[0], a[1]), fmaxf(a[2], a[3])),
                             fmaxf(fmaxf(b[0], b[1]), fmaxf(b[2], b[3])));
            tm = fmaxf(tm, __shfl_xor(tm, 1, 64));
            tm = fmaxf(tm, __shfl_xor(tm, 2, 64));
            tm = fmaxf(tm, __shfl_xor(tm, 4, 64));
            float Mo = Mrow[brow];
            float Mn = fmaxf(Mo, tm);
            float p[8];
#pragma unroll
            for (int i = 0; i < 4; ++i) p[i] = __expf(a[i] - Mn);
#pragma unroll
            for (int i = 0; i < 4; ++i) p[4 + i] = __expf(b[i] - Mn);
            float ts = 0.f;
#pragma unroll
            for (int i = 0; i < 8; ++i) ts += p[i];
            ts += __shfl_xor(ts, 1, 64);
            ts += __shfl_xor(ts, 2, 64);
            ts += __shfl_xor(ts, 4, 64);
            int4 pkv;
            pkv.x = (int)((uint)f2bf(p[0]) | ((uint)f2bf(p[1]) << 16));
            pkv.y = (int)((uint)f2bf(p[2]) | ((uint)f2bf(p[3]) << 16));
            pkv.z = (int)((uint)f2bf(p[4]) | ((uint)f2bf(p[5]) << 16));
            pkv.w = (int)((uint)f2bf(p[6]) | ((uint)f2bf(p[7]) << 16));
            *(int4*)&Pb[brow][cbase] = pkv;
            if (bj == 0) {
                float f = __expf(Mo - Mn);
                Mrow[brow] = Mn;
                Srow[brow] = Srow[brow] * f + ts;
                Frow[brow] = f;
            }
        }
        bar_vm(pk);   // Pb/Frow visible AND V landed (K prefetch still in flight)

        // ---- rescale + PV (swizzled V reads)
        {
            int row4 = mh * 16 + (l >> 4) * 4;
#pragma unroll
            for (int j = 0; j < 4; ++j) {
                float fj = Frow[row4 + j];
                o0[j] *= fj;
                o1[j] *= fj;
            }
            int kbase = (l >> 4) * 8;
            int prow = mh * 16 + (l & 15);
            bf16x8 p0 = *(const bf16x8*)&Pb[prow][kbase];
            bf16x8 p1 = *(const bf16x8*)&Pb[prow][kbase + 32];
            int kb_ = l >> 4;
            int d0 = nh * 32 + (l & 15), d1 = d0 + 16;
            bf16x8 v00 = *(const bf16x8*)&Vs[d0 * 64 + ((kb_ ^ (d0 & 7)) * 8)];
            bf16x8 v01 = *(const bf16x8*)&Vs[d0 * 64 + (((kb_ + 4) ^ (d0 & 7)) * 8)];
            bf16x8 v10 = *(const bf16x8*)&Vs[d1 * 64 + ((kb_ ^ (d1 & 7)) * 8)];
            bf16x8 v11 = *(const bf16x8*)&Vs[d1 * 64 + (((kb_ + 4) ^ (d1 & 7)) * 8)];
            __builtin_amdgcn_s_setprio(1);
            o0 = __builtin_amdgcn_mfma_f32_16x16x32_bf16(p0, v00, o0, 0, 0, 0);
            o0 = __builtin_amdgcn_mfma_f32_16x16x32_bf16(p1, v01, o0, 0, 0, 0);
            o1 = __builtin_amdgcn_mfma_f32_16x16x32_bf16(p0, v10, o1, 0, 0, 0);
            o1 = __builtin_amdgcn_mfma_f32_16x16x32_bf16(p1, v11, o1, 0, 0, 0);
            __builtin_amdgcn_s_setprio(0);
        }
        __syncthreads();   // full drain: K prefetch landed, all reads of buf/Vs done
    }

    // ---- write partials (unnormalized o, plus M,S)
    {
        int row4 = mh * 16 + (l >> 4) * 4;
        int c0 = nh * 32 + (l & 15);
#pragma unroll
        for (int j = 0; j < 4; ++j) {
            int r = row4 + j;
            float* dst = opart + ((size_t)ks * NN + n0 + r) * HH + head * HD;
            dst[c0] = o0[j];
            dst[c0 + 16] = o1[j];
        }
    }
    if (t < 32) {
        Mp[((size_t)ks * NHH + head) * NN + n0 + t] = Mrow[t];
        Sp[((size_t)ks * NHH + head) * NN + n0 + t] = Srow[t];
    }
}

// combine 2 partials -> bf16 attention output
__global__ __launch_bounds__(256) void attn_combine(const float* __restrict__ opart,
                                                    const float* __restrict__ Mp,
                                                    const float* __restrict__ Sp,
                                                    ushort* __restrict__ aob) {
    int i = blockIdx.x * 256 + threadIdx.x;
    int row = i >> 9, col = i & 511;
    int head = col >> 6;
    float m0 = Mp[(size_t)head * NN + row];
    float m1 = Mp[((size_t)NHH + head) * NN + row];
    float s0 = Sp[(size_t)head * NN + row];
    float s1 = Sp[((size_t)NHH + head) * NN + row];
    float m = fmaxf(m0, m1);
    float w0 = __expf(m0 - m), w1 = __expf(m1 - m);
    float ov0 = opart[(size_t)row * HH + col];
    float ov1 = opart[((size_t)NN + row) * HH + col];
    aob[i] = f2bf((ov0 * w0 + ov1 * w1) / (s0 * w0 + s1 * w1));
}

// ---------------- LayerNorm(out = LN(a + b) * g + be); optional bf16 copy
template<int BF16OUT>
__global__ __launch_bounds__(256) void ln_kernel(const float* __restrict__ a,
                                                 const float* __restrict__ b,
                                                 const float* __restrict__ g,
                                                 const float* __restrict__ be,
                                                 float* __restrict__ out,
                                                 ushort* __restrict__ outb) {
    int row = blockIdx.x * 4 + (threadIdx.x >> 6);
    int lane = threadIdx.x & 63;
    const float* pa = a + (size_t)row * HH;
    const float* pb = b + (size_t)row * HH;
    float x[8];
    float s = 0.f;
#pragma unroll
    for (int i = 0; i < 8; ++i) { x[i] = pa[lane + i * 64] + pb[lane + i * 64]; s += x[i]; }
#pragma unroll
    for (int off = 32; off > 0; off >>= 1) s += __shfl_xor(s, off, 64);
    float mean = s * (1.f / 512.f);
    float vs = 0.f;
#pragma unroll
    for (int i = 0; i < 8; ++i) { float d = x[i] - mean; vs += d * d; }
#pragma unroll
    for (int off = 32; off > 0; off >>= 1) vs += __shfl_xor(vs, off, 64);
    float rs = rsqrtf(vs * (1.f / 512.f) + 1e-5f);
    float* po = out + (size_t)row * HH;
    ushort* pob = outb + (size_t)row * HH;
#pragma unroll
    for (int i = 0; i < 8; ++i) {
        float v = (x[i] - mean) * rs * g[lane + i * 64] + be[lane + i * 64];
        po[lane + i * 64] = v;
        if (BF16OUT) pob[lane + i * 64] = f2bf(v);
    }
}

extern "C" void kernel_launch(void* const* d_in, const int* in_sizes, int n_in,
                              void* d_out, int out_size, void* d_ws, size_t ws_size,
                              hipStream_t stream) {
    const float* x   = (const float*)d_in[0];
    const int*  eidx = (const int*)d_in[1];
    const float* ea  = (const float*)d_in[2];
    const float* Wn = (const float*)d_in[3];  const float* bn = (const float*)d_in[4];
    const float* We = (const float*)d_in[5];  const float* be = (const float*)d_in[6];
    const float* Wq = (const float*)d_in[7];  const float* bq = (const float*)d_in[8];
    const float* Wk = (const float*)d_in[9];  const float* bk = (const float*)d_in[10];
    const float* Wv = (const float*)d_in[11]; const float* bv = (const float*)d_in[12];
    const float* Wo = (const float*)d_in[13]; const float* bo = (const float*)d_in[14];
    const float* W1 = (const float*)d_in[15]; const float* b1 = (const float*)d_in[16];
    const float* W2 = (const float*)d_in[17]; const float* b2 = (const float*)d_in[18];
    const float* g1 = (const float*)d_in[19]; const float* be1 = (const float*)d_in[20];
    const float* g2 = (const float*)d_in[21]; const float* be2 = (const float*)d_in[22];
    float* out = (float*)d_out;

    // workspace carve (bytes, 256-aligned)
    char* base = (char*)d_ws;
    size_t off = 0;
    auto carve = [&](size_t bytes) { void* p = base + off; off = (off + bytes + 255) & ~(size_t)255; return p; };
    float*  h    = (float*)carve((size_t)NN * HH * 4);
    ushort* hb   = (ushort*)carve((size_t)NN * HH * 2);
    // [po, ff1b, qb, kbf] contiguous 16 MB -> aliased as lastE during setup
    float*  po   = (float*)carve((size_t)NN * HH * 4);
    ushort* ff1b = (ushort*)carve((size_t)NN * 4 * HH * 2);   // also opart (8 MB f32)
    ushort* qb   = (ushort*)carve((size_t)NN * HH * 2);
    ushort* kbf  = (ushort*)carve((size_t)NN * HH * 2);
    ushort* vtb  = (ushort*)carve((size_t)NN * HH * 2);
    ushort* aob  = (ushort*)carve((size_t)NN * HH * 2);
    ushort* xb   = (ushort*)carve((size_t)NN * NF_ * 2);
    ushort* WnT  = (ushort*)carve((size_t)HH * NF_ * 2);
    ushort* WqkvT= (ushort*)carve((size_t)3 * HH * HH * 2);
    ushort* WoT  = (ushort*)carve((size_t)HH * HH * 2);
    ushort* W1T  = (ushort*)carve((size_t)4 * HH * HH * 2);
    ushort* W2T  = (ushort*)carve((size_t)4 * HH * HH * 2);
    float*  bqkv = (float*)carve((size_t)3 * HH * 4);
    float*  eb   = (float*)carve((size_t)EE * NHH * 4);
    float*  csr_b= (float*)carve((size_t)EE * NHH * 4);
    float*  Mp   = (float*)carve((size_t)KSPLIT * NHH * NN * 4);
    float*  Sp   = (float*)carve((size_t)KSPLIT * NHH * NN * 4);
    int* cnt     = (int*)carve((size_t)NN * 4);
    int* rowptr  = (int*)carve((size_t)(NN + 1) * 4);
    int* rowoff  = (int*)carve((size_t)NN * 4);
    int* csr_dst = (int*)carve((size_t)EE * 4);
    int* lastE = (int*)po;            // setup alias (po+ff1b+qb+kbf = 16 MB)
    float* opart = (float*)ff1b;      // attention partials alias FF intermediate

    // ---- setup
    hipMemsetAsync(lastE, 0xFF, (size_t)NN * NN * 4, stream);
    hipMemsetAsync(cnt, 0, (size_t)NN * 4, stream);

    xcvt<<<(NN * NF_ + 255) / 256, 256, 0, stream>>>(x, xb, NN * NF_);
    wtrans<<<dim3(HH / 32, NF_ / 32), 256, 0, stream>>>(Wn, WnT, NF_, HH, 0);
    wtrans<<<dim3(HH / 32, HH / 32), 256, 0, stream>>>(Wq, WqkvT, HH, HH, 0);
    wtrans<<<dim3(HH / 32, HH / 32), 256, 0, stream>>>(Wk, WqkvT, HH, HH, 512);
    wtrans<<<dim3(HH / 32, HH / 32), 256, 0, stream>>>(Wv, WqkvT, HH, HH, 1024);
    wtrans<<<dim3(HH / 32, HH / 32), 256, 0, stream>>>(Wo, WoT, HH, HH, 0);
    wtrans<<<dim3(4 * HH / 32, HH / 32), 256, 0, stream>>>(W1, W1T, HH, 4 * HH, 0);
    wtrans<<<dim3(HH / 32, 4 * HH / 32), 256, 0, stream>>>(W2, W2T, 4 * HH, HH, 0);
    bconcat<<<6, 256, 0, stream>>>(bq, bk, bv, bqkv);

    ebias_kernel<<<EE / 256, 256, 0, stream>>>(ea, We, be, eb);
    amax_kernel<<<EE / 256, 256, 0, stream>>>(eidx, lastE);
    count_kernel<<<EE / 256, 256, 0, stream>>>(eidx, lastE, cnt);
    scan2048<<<1, 256, 0, stream>>>(cnt, rowptr, rowoff);
    fill_kernel<<<EE / 256, 256, 0, stream>>>(eidx, lastE, eb, rowoff, csr_dst, csr_b);

    // h = x @ Wn + bn  (f32 + bf16)
    gemm_mfma<64, 1, 0><<<dim3(HH / 64, NN / 128), 256, 0, stream>>>(
        xb, WnT, bn, h, hb, nullptr, nullptr, nullptr, NN, HH, NF_);

    // ---- transformer layers
    for (int d = 0; d < DEPTH; ++d) {
        gemm_mfma<128, 3, 0><<<dim3(3 * HH / 128, NN / 128), 256, 0, stream>>>(
            hb, WqkvT, bqkv, nullptr, nullptr, qb, kbf, vtb, NN, 3 * HH, HH);
        attn_mfma<<<dim3(NN / 32, NHH, KSPLIT), 256, 0, stream>>>(
            qb, kbf, vtb, rowptr, csr_dst, csr_b, opart, Mp, Sp);
        attn_combine<<<NN * HH / 256, 256, 0, stream>>>(opart, Mp, Sp, aob);
        gemm_mfma<64, 0, 0><<<dim3(HH / 64, NN / 128), 256, 0, stream>>>(
            aob, WoT, bo, po, nullptr, nullptr, nullptr, nullptr, NN, HH, HH);
        ln_kernel<1><<<NN / 4, 256, 0, stream>>>(h, po, g1, be1, h, hb);
        gemm_mfma<128, 2, 1><<<dim3(4 * HH / 128, NN / 128), 256, 0, stream>>>(
            hb, W1T, b1, nullptr, ff1b, nullptr, nullptr, nullptr, NN, 4 * HH, HH);
        gemm_mfma<64, 0, 0><<<dim3(HH / 64, NN / 128), 256, 0, stream>>>(
            ff1b, W2T, b2, po, nullptr, nullptr, nullptr, nullptr, NN, HH, 4 * HH);
        float* dst = (d == DEPTH - 1) ? out : h;
        ln_kernel<1><<<NN / 4, 256, 0, stream>>>(h, po, g2, be2, dst, hb);
    }
    (void)in_sizes; (void)n_in; (void)out_size; (void)ws_size;
}

// Round 6
// 719.363 us; speedup vs baseline: 1.5897x; 1.5897x over previous
//
#include <hip/hip_runtime.h>
#include <hip/hip_bf16.h>

// Problem constants (fixed shapes)
#define NN 2048      // nodes
#define EE 65536     // edges
#define NF_ 128
#define HH 512
#define NHH 8
#define HD 64
#define DEPTH 5
#define KSPLIT 2
#define KEYS_PER (NN / KSPLIT)   // 1024
#define NTILE (KEYS_PER / 64)    // 16
#define NTILE_TOT (NN / 64)      // 32
#define LOG2E 1.4426950408889634f

typedef __attribute__((ext_vector_type(8))) short bf16x8;
typedef __attribute__((ext_vector_type(4))) float f32x4;

__device__ __forceinline__ ushort f2bf(float x) {
    uint u = __builtin_bit_cast(uint, x);
    u += 0x7fffu + ((u >> 16) & 1u);
    return (ushort)(u >> 16);
}

#define GLD16(gp, lp)                                                          \
    __builtin_amdgcn_global_load_lds(                                          \
        (const __attribute__((address_space(1))) unsigned int*)(gp),           \
        (__attribute__((address_space(3))) unsigned int*)(lp), 16, 0, 0)

// raw barrier: LDS visible, vmem loads stay in flight
__device__ __forceinline__ void bar_lgkm() {
    asm volatile("s_waitcnt lgkmcnt(0)" ::: "memory");
    __builtin_amdgcn_s_barrier();
    __builtin_amdgcn_sched_barrier(0);
}
__device__ __forceinline__ void bar_vm(int pk) {
    if (pk) asm volatile("s_waitcnt vmcnt(2) lgkmcnt(0)" ::: "memory");
    else    asm volatile("s_waitcnt vmcnt(0) lgkmcnt(0)" ::: "memory");
    __builtin_amdgcn_s_barrier();
    __builtin_amdgcn_sched_barrier(0);
}

// ---------------- bf16 MFMA GEMM: C = A[M,K] @ Bt[N,K]^T + bias
// OUT: 0 = f32 C; 1 = f32 C + bf16 Cb; 2 = bf16 Cb; 3 = qkv scatter (q/k head-major, v transposed)
template<int BN, int OUT, int RELU>
__global__ __launch_bounds__(256) void gemm_mfma(const ushort* __restrict__ A,
                                                 const ushort* __restrict__ Bt,
                                                 const float* __restrict__ bias,
                                                 float* __restrict__ C,
                                                 ushort* __restrict__ Cb,
                                                 ushort* __restrict__ qb,
                                                 ushort* __restrict__ kb,
                                                 ushort* __restrict__ vtb,
                                                 int M, int N, int K) {
    constexpr int WN = BN / 2;
    constexpr int NR = WN / 16;
    __shared__ __align__(16) ushort As[2][128 * 64];
    __shared__ __align__(16) ushort Bs[2][BN * 64];
    const int t = threadIdx.x;
    const int w = t >> 6, l = t & 63;
    const int wr = w >> 1, wc = w & 1;
    const int m0 = blockIdx.y * 128, n0 = blockIdx.x * BN;

    f32x4 acc[4][NR];
#pragma unroll
    for (int m = 0; m < 4; ++m)
#pragma unroll
        for (int n = 0; n < NR; ++n) acc[m][n] = (f32x4){0.f, 0.f, 0.f, 0.f};

    const int srow = t >> 3, sch = t & 7;
    auto stage = [&](int buf, int kt) {
#pragma unroll
        for (int r = 0; r < 4; ++r) {
            int rr = r * 32 + srow;
            int c = sch ^ (rr & 7);                   // inverse swizzle on SOURCE
            GLD16(A + (size_t)(m0 + rr) * K + kt * 64 + c * 8,
                  &As[buf][rr * 64 + sch * 8]);       // linear LDS dest
        }
#pragma unroll
        for (int r = 0; r < BN / 32; ++r) {
            int rr = r * 32 + srow;
            int c = sch ^ (rr & 7);
            GLD16(Bt + (size_t)(n0 + rr) * K + kt * 64 + c * 8,
                  &Bs[buf][rr * 64 + sch * 8]);
        }
    };

    stage(0, 0);
    const int NT = K / 64;
    for (int kt = 0; kt < NT; ++kt) {
        __syncthreads();
        if (kt + 1 < NT) stage((kt + 1) & 1, kt + 1);
        const int buf = kt & 1;
#pragma unroll
        for (int kk = 0; kk < 2; ++kk) {
            bf16x8 af[4], bfr[NR];
#pragma unroll
            for (int m = 0; m < 4; ++m) {
                int R = wr * 64 + m * 16 + (l & 15);
                int c = kk * 4 + (l >> 4);
                af[m] = *(const bf16x8*)&As[buf][R * 64 + (c ^ (R & 7)) * 8];
            }
#pragma unroll
            for (int n = 0; n < NR; ++n) {
                int R = wc * WN + n * 16 + (l & 15);
                int c = kk * 4 + (l >> 4);
                bfr[n] = *(const bf16x8*)&Bs[buf][R * 64 + (c ^ (R & 7)) * 8];
            }
#pragma unroll
            for (int m = 0; m < 4; ++m)
#pragma unroll
                for (int n = 0; n < NR; ++n)
                    acc[m][n] = __builtin_amdgcn_mfma_f32_16x16x32_bf16(af[m], bfr[n], acc[m][n], 0, 0, 0);
        }
    }

#pragma unroll
    for (int m = 0; m < 4; ++m) {
        int row = m0 + wr * 64 + m * 16 + (l >> 4) * 4;
#pragma unroll
        for (int n = 0; n < NR; ++n) {
            int col = n0 + wc * WN + n * 16 + (l & 15);
            float bv = bias[col];
#pragma unroll
            for (int j = 0; j < 4; ++j) {
                float vv = acc[m][n][j] + bv;
                if (RELU) vv = fmaxf(vv, 0.f);
                int r = row + j;
                if (OUT == 0) {
                    C[(size_t)r * N + col] = vv;
                } else if (OUT == 1) {
                    C[(size_t)r * N + col] = vv;
                    Cb[(size_t)r * N + col] = f2bf(vv);
                } else if (OUT == 2) {
                    Cb[(size_t)r * N + col] = f2bf(vv);
                } else {
                    int type = col >> 9, head = (col >> 6) & 7, dd = col & 63;
                    ushort bv16 = f2bf(vv);
                    if (type == 0) qb[((size_t)head * NN + r) * 64 + dd] = bv16;
                    else if (type == 1) kb[((size_t)head * NN + r) * 64 + dd] = bv16;
                    else vtb[((size_t)head * 64 + dd) * NN + r] = bv16;
                }
            }
        }
    }
}

// ---------------- setup converts
__global__ __launch_bounds__(256) void xcvt(const float* __restrict__ x, ushort* __restrict__ xb, int n) {
    int i = blockIdx.x * 256 + threadIdx.x;
    if (i < n) xb[i] = f2bf(x[i]);
}

__global__ __launch_bounds__(256) void wtrans(const float* __restrict__ W, ushort* __restrict__ WT,
                                              int K, int N, int rowoff) {
    __shared__ float tile[32][33];
    int n0 = blockIdx.x * 32, k0 = blockIdx.y * 32;
    int tc = threadIdx.x & 31, tr = threadIdx.x >> 5;
#pragma unroll
    for (int i = 0; i < 32; i += 8) tile[tr + i][tc] = W[(size_t)(k0 + tr + i) * N + n0 + tc];
    __syncthreads();
#pragma unroll
    for (int i = 0; i < 32; i += 8)
        WT[(size_t)(rowoff + n0 + tr + i) * K + k0 + tc] = f2bf(tile[tc][tr + i]);
}

__global__ __launch_bounds__(256) void bconcat(const float* __restrict__ a, const float* __restrict__ b,
                                               const float* __restrict__ c, float* __restrict__ o) {
    int i = blockIdx.x * 256 + threadIdx.x;
    if (i < 1536) o[i] = i < 512 ? a[i] : (i < 1024 ? b[i - 512] : c[i - 1024]);
}

// ---------------- e_bias = edge_attr @ We + be
__global__ __launch_bounds__(256) void ebias_kernel(const float* __restrict__ ea,
                                                    const float* __restrict__ We,
                                                    const float* __restrict__ be,
                                                    float* __restrict__ eb) {
    int e = blockIdx.x * 256 + threadIdx.x;
    float a[16];
#pragma unroll
    for (int i = 0; i < 16; ++i) a[i] = ea[(size_t)e * 16 + i];
#pragma unroll
    for (int j = 0; j < 8; ++j) {
        float s = be[j];
#pragma unroll
        for (int i = 0; i < 16; ++i) s += a[i] * We[i * 8 + j];
        eb[(size_t)e * 8 + j] = s;
    }
}

// ---------------- dedupe: last edge index wins per (src,dst)
__global__ __launch_bounds__(256) void amax_kernel(const int* __restrict__ eidx, int* __restrict__ lastE) {
    int e = blockIdx.x * 256 + threadIdx.x;
    int s = eidx[e], d = eidx[EE + e];
    atomicMax(&lastE[s * NN + d], e);
}

__global__ __launch_bounds__(256) void count_kernel(const int* __restrict__ eidx,
                                                    const int* __restrict__ lastE,
                                                    int* __restrict__ cnt) {
    int e = blockIdx.x * 256 + threadIdx.x;
    int s = eidx[e], d = eidx[EE + e];
    if (lastE[s * NN + d] == e) atomicAdd(&cnt[s], 1);
}

__global__ __launch_bounds__(256) void scan2048(const int* __restrict__ cnt,
                                                int* __restrict__ rowptr) {
    __shared__ int sums[256];
    int t = threadIdx.x;
    int loc[8];
    int s = 0;
#pragma unroll
    for (int i = 0; i < 8; ++i) { loc[i] = s; s += cnt[t * 8 + i]; }
    sums[t] = s;
    __syncthreads();
    for (int off = 1; off < 256; off <<= 1) {
        int v = (t >= off) ? sums[t - off] : 0;
        __syncthreads();
        sums[t] += v;
        __syncthreads();
    }
    int base = (t == 0) ? 0 : sums[t - 1];
#pragma unroll
    for (int i = 0; i < 8; ++i) rowptr[t * 8 + i] = base + loc[i];
    if (t == 255) rowptr[NN] = sums[255];
}

// ---------------- (row, key-tile) bucketing of bias entries (layer-invariant)
__global__ __launch_bounds__(256) void rt_count(const int* __restrict__ eidx,
                                                const int* __restrict__ lastE,
                                                int* __restrict__ cnt2) {
    int e = blockIdx.x * 256 + threadIdx.x;
    int s = eidx[e], d = eidx[EE + e];
    if (lastE[s * NN + d] == e) atomicAdd(&cnt2[s * NTILE_TOT + (d >> 6)], 1);
}

__global__ __launch_bounds__(256) void rt_scan(const int* __restrict__ rowptr,
                                               const int* __restrict__ cnt2,
                                               int* __restrict__ rtptr,
                                               int* __restrict__ rtoff) {
    int row = blockIdx.x * 256 + threadIdx.x;
    if (row >= NN) return;
    int base = rowptr[row];
#pragma unroll
    for (int t = 0; t < NTILE_TOT; ++t) {
        rtptr[row * NTILE_TOT + t] = base;
        rtoff[row * NTILE_TOT + t] = base;
        base += cnt2[row * NTILE_TOT + t];
    }
    if (row == NN - 1) rtptr[NN * NTILE_TOT] = base;
}

// fill buckets: dst stored relative to tile (0..63); bias pre-scaled by log2e
__global__ __launch_bounds__(256) void rt_fill(const int* __restrict__ eidx,
                                               const int* __restrict__ lastE,
                                               const float* __restrict__ eb,
                                               int* __restrict__ rtoff,
                                               int* __restrict__ csr_dst,
                                               float* __restrict__ csr_b) {
    int e = blockIdx.x * 256 + threadIdx.x;
    int s = eidx[e], d = eidx[EE + e];
    if (lastE[s * NN + d] == e) {
        int pos = atomicAdd(&rtoff[s * NTILE_TOT + (d >> 6)], 1);
        csr_dst[pos] = d & 63;
#pragma unroll
        for (int j = 0; j < 8; ++j) csr_b[(size_t)pos * 8 + j] = eb[(size_t)e * 8 + j] * LOG2E;
    }
}

// ---------------- split-K flash attention with MFMA bf16 (log2-space softmax)
// grid (NN/32, NHH, KSPLIT). 3 barriers/tile; K dbuf + V staged via global_load_lds (XOR swizzle).
__global__ __launch_bounds__(256) void attn_mfma(const ushort* __restrict__ qb,
                                                 const ushort* __restrict__ kb,
                                                 const ushort* __restrict__ vtb,
                                                 const int* __restrict__ rtptr,
                                                 const int* __restrict__ csr_dst,
                                                 const float* __restrict__ csr_b,
                                                 float* __restrict__ opart,
                                                 float* __restrict__ Mp,
                                                 float* __restrict__ Sp) {
    const int n0 = blockIdx.x * 32;
    const int head = blockIdx.y;
    const int ks = blockIdx.z;
    const int t = threadIdx.x;
    const int w = t >> 6, l = t & 63;
    const int mh = w & 1, nh = w >> 1;
    const float c1 = 0.125f * LOG2E;   // qk scale in log2 space

    __shared__ __align__(16) ushort Ks2[2][64 * 64];   // K dbuf, swizzled
    __shared__ __align__(16) ushort Vs[64 * 64];       // V single buf, swizzled
    __shared__ __align__(16) float  Sl[32][68];
    __shared__ __align__(16) ushort Pb[32][72];
    __shared__ float Mrow[32], Srow[32], Frow[32];
    __shared__ int Rt[32][17];                          // bucket boundaries for this block

    bf16x8 qf0, qf1;
    {
        int r = n0 + mh * 16 + (l & 15);
        const ushort* qp = qb + ((size_t)head * NN + r) * HD + ((l >> 4) * 8);
        qf0 = *(const bf16x8*)qp;
        qf1 = *(const bf16x8*)(qp + 32);
    }
    if (t < 32) { Mrow[t] = -1e30f; Srow[t] = 0.f; }
    for (int i = t; i < 32 * 17; i += 256) {
        int r = i / 17, c = i % 17;
        Rt[r][c] = rtptr[(n0 + r) * NTILE_TOT + ks * NTILE + c];
    }
    const int brow = t >> 3, bj = t & 7;
    f32x4 o0 = {0.f, 0.f, 0.f, 0.f}, o1 = {0.f, 0.f, 0.f, 0.f};

    auto stageK = [&](int buf, int tile) {
        int m0k = ks * KEYS_PER + tile * 64;
#pragma unroll
        for (int s = 0; s < 2; ++s) {
            int slot = t + s * 256;
            int rr = slot >> 3, blk = slot & 7, sb = blk ^ (rr & 7);
            GLD16(kb + ((size_t)head * NN + m0k + rr) * 64 + sb * 8,
                  &Ks2[buf][rr * 64 + blk * 8]);
        }
    };
    auto stageV = [&](int tile) {
        int m0k = ks * KEYS_PER + tile * 64;
#pragma unroll
        for (int s = 0; s < 2; ++s) {
            int slot = t + s * 256;
            int rr = slot >> 3, blk = slot & 7, sb = blk ^ (rr & 7);
            GLD16(vtb + ((size_t)head * 64 + rr) * NN + m0k + sb * 8,
                  &Vs[rr * 64 + blk * 8]);
        }
    };

    stageK(0, 0);
    __syncthreads();   // K(0) landed, Mrow/Rt visible

    for (int tt = 0; tt < NTILE; ++tt) {
        const int buf = tt & 1;
        const int pk = (tt + 1 < NTILE);
        stageV(tt);
        if (pk) stageK(buf ^ 1, tt + 1);

        // ---- QK^T from Ks2[buf] (swizzled reads)
        {
            const ushort* Kb_ = &Ks2[buf][0];
            int db = l >> 4;
            int key0 = nh * 32 + (l & 15), key1 = key0 + 16;
            bf16x8 ka0 = *(const bf16x8*)&Kb_[key0 * 64 + ((db ^ (key0 & 7)) * 8)];
            bf16x8 ka1 = *(const bf16x8*)&Kb_[key0 * 64 + (((db + 4) ^ (key0 & 7)) * 8)];
            bf16x8 kb0 = *(const bf16x8*)&Kb_[key1 * 64 + ((db ^ (key1 & 7)) * 8)];
            bf16x8 kb1 = *(const bf16x8*)&Kb_[key1 * 64 + (((db + 4) ^ (key1 & 7)) * 8)];
            f32x4 s0 = {0.f, 0.f, 0.f, 0.f}, s1 = {0.f, 0.f, 0.f, 0.f};
            __builtin_amdgcn_s_setprio(1);
            s0 = __builtin_amdgcn_mfma_f32_16x16x32_bf16(qf0, ka0, s0, 0, 0, 0);
            s0 = __builtin_amdgcn_mfma_f32_16x16x32_bf16(qf1, ka1, s0, 0, 0, 0);
            s1 = __builtin_amdgcn_mfma_f32_16x16x32_bf16(qf0, kb0, s1, 0, 0, 0);
            s1 = __builtin_amdgcn_mfma_f32_16x16x32_bf16(qf1, kb1, s1, 0, 0, 0);
            __builtin_amdgcn_s_setprio(0);
            int row = mh * 16 + (l >> 4) * 4;
            int c0 = nh * 32 + (l & 15);
#pragma unroll
            for (int j = 0; j < 4; ++j) {
                Sl[row + j][c0] = s0[j] * c1;
                Sl[row + j][c0 + 16] = s1[j] * c1;
            }
        }
        bar_lgkm();   // Sl visible; staging loads stay in flight

        // ---- bias (pre-bucketed, ~1 entry/row/tile) + online softmax (log2 space)
        {
            const int cbase = bj * 8;
            const int p0 = Rt[brow][tt], p1 = Rt[brow][tt + 1];
            for (int e = p0; e < p1; ++e) {
                int dd = csr_dst[e];                 // 0..63 within tile
                if ((dd >> 3) == bj) Sl[brow][dd] += csr_b[(size_t)e * 8 + head];
            }
            f32x4 a = *(const f32x4*)&Sl[brow][cbase];
            f32x4 b = *(const f32x4*)&Sl[brow][cbase + 4];
            float tm = fmaxf(fmaxf(fmaxf(a[0], a[1]), fmaxf(a[2], a[3])),
                             fmaxf(fmaxf(b[0], b[1]), fmaxf(b[2], b[3])));
            tm = fmaxf(tm, __shfl_xor(tm, 1, 64));
            tm = fmaxf(tm, __shfl_xor(tm, 2, 64));
            tm = fmaxf(tm, __shfl_xor(tm, 4, 64));
            float Mo = Mrow[brow];
            float Mn = fmaxf(Mo, tm);
            float p[8];
#pragma unroll
            for (int i = 0; i < 4; ++i) p[i] = exp2f(a[i] - Mn);
#pragma unroll
            for (int i = 0; i < 4; ++i) p[4 + i] = exp2f(b[i] - Mn);
            float ts = 0.f;
#pragma unroll
            for (int i = 0; i < 8; ++i) ts += p[i];
            ts += __shfl_xor(ts, 1, 64);
            ts += __shfl_xor(ts, 2, 64);
            ts += __shfl_xor(ts, 4, 64);
            int4 pkv;
            pkv.x = (int)((uint)f2bf(p[0]) | ((uint)f2bf(p[1]) << 16));
            pkv.y = (int)((uint)f2bf(p[2]) | ((uint)f2bf(p[3]) << 16));
            pkv.z = (int)((uint)f2bf(p[4]) | ((uint)f2bf(p[5]) << 16));
            pkv.w = (int)((uint)f2bf(p[6]) | ((uint)f2bf(p[7]) << 16));
            *(int4*)&Pb[brow][cbase] = pkv;
            if (bj == 0) {
                float f = exp2f(Mo - Mn);
                Mrow[brow] = Mn;
                Srow[brow] = Srow[brow] * f + ts;
                Frow[brow] = f;
            }
        }
        bar_vm(pk);   // Pb/Frow visible AND V landed (K prefetch may stay in flight)

        // ---- rescale + PV (swizzled V reads)
        {
            int row4 = mh * 16 + (l >> 4) * 4;
#pragma unroll
            for (int j = 0; j < 4; ++j) {
                float fj = Frow[row4 + j];
                o0[j] *= fj;
                o1[j] *= fj;
            }
            int kbase = (l >> 4) * 8;
            int prow = mh * 16 + (l & 15);
            bf16x8 p0 = *(const bf16x8*)&Pb[prow][kbase];
            bf16x8 p1 = *(const bf16x8*)&Pb[prow][kbase + 32];
            int kb_ = l >> 4;
            int d0 = nh * 32 + (l & 15), d1 = d0 + 16;
            bf16x8 v00 = *(const bf16x8*)&Vs[d0 * 64 + ((kb_ ^ (d0 & 7)) * 8)];
            bf16x8 v01 = *(const bf16x8*)&Vs[d0 * 64 + (((kb_ + 4) ^ (d0 & 7)) * 8)];
            bf16x8 v10 = *(const bf16x8*)&Vs[d1 * 64 + ((kb_ ^ (d1 & 7)) * 8)];
            bf16x8 v11 = *(const bf16x8*)&Vs[d1 * 64 + (((kb_ + 4) ^ (d1 & 7)) * 8)];
            __builtin_amdgcn_s_setprio(1);
            o0 = __builtin_amdgcn_mfma_f32_16x16x32_bf16(p0, v00, o0, 0, 0, 0);
            o0 = __builtin_amdgcn_mfma_f32_16x16x32_bf16(p1, v01, o0, 0, 0, 0);
            o1 = __builtin_amdgcn_mfma_f32_16x16x32_bf16(p0, v10, o1, 0, 0, 0);
            o1 = __builtin_amdgcn_mfma_f32_16x16x32_bf16(p1, v11, o1, 0, 0, 0);
            __builtin_amdgcn_s_setprio(0);
        }
        __syncthreads();
    }

    // ---- write partials (unnormalized o, plus M,S; M in log2 units)
    {
        int row4 = mh * 16 + (l >> 4) * 4;
        int c0 = nh * 32 + (l & 15);
#pragma unroll
        for (int j = 0; j < 4; ++j) {
            int r = row4 + j;
            float* dst = opart + ((size_t)ks * NN + n0 + r) * HH + head * HD;
            dst[c0] = o0[j];
            dst[c0 + 16] = o1[j];
        }
    }
    if (t < 32) {
        Mp[((size_t)ks * NHH + head) * NN + n0 + t] = Mrow[t];
        Sp[((size_t)ks * NHH + head) * NN + n0 + t] = Srow[t];
    }
}

// combine 2 partials -> bf16 attention output (log2-space M)
__global__ __launch_bounds__(256) void attn_combine(const float* __restrict__ opart,
                                                    const float* __restrict__ Mp,
                                                    const float* __restrict__ Sp,
                                                    ushort* __restrict__ aob) {
    int i = blockIdx.x * 256 + threadIdx.x;
    int row = i >> 9, col = i & 511;
    int head = col >> 6;
    float m0 = Mp[(size_t)head * NN + row];
    float m1 = Mp[((size_t)NHH + head) * NN + row];
    float s0 = Sp[(size_t)head * NN + row];
    float s1 = Sp[((size_t)NHH + head) * NN + row];
    float m = fmaxf(m0, m1);
    float w0 = exp2f(m0 - m), w1 = exp2f(m1 - m);
    float ov0 = opart[(size_t)row * HH + col];
    float ov1 = opart[((size_t)NN + row) * HH + col];
    aob[i] = f2bf((ov0 * w0 + ov1 * w1) / (s0 * w0 + s1 * w1));
}

// ---------------- LayerNorm(out = LN(a + b) * g + be); optional bf16 copy
template<int BF16OUT>
__global__ __launch_bounds__(256) void ln_kernel(const float* __restrict__ a,
                                                 const float* __restrict__ b,
                                                 const float* __restrict__ g,
                                                 const float* __restrict__ be,
                                                 float* __restrict__ out,
                                                 ushort* __restrict__ outb) {
    int row = blockIdx.x * 4 + (threadIdx.x >> 6);
    int lane = threadIdx.x & 63;
    const float* pa = a + (size_t)row * HH;
    const float* pb = b + (size_t)row * HH;
    float x[8];
    float s = 0.f;
#pragma unroll
    for (int i = 0; i < 8; ++i) { x[i] = pa[lane + i * 64] + pb[lane + i * 64]; s += x[i]; }
#pragma unroll
    for (int off = 32; off > 0; off >>= 1) s += __shfl_xor(s, off, 64);
    float mean = s * (1.f / 512.f);
    float vs = 0.f;
#pragma unroll
    for (int i = 0; i < 8; ++i) { float d = x[i] - mean; vs += d * d; }
#pragma unroll
    for (int off = 32; off > 0; off >>= 1) vs += __shfl_xor(vs, off, 64);
    float rs = rsqrtf(vs * (1.f / 512.f) + 1e-5f);
    float* po = out + (size_t)row * HH;
    ushort* pob = outb + (size_t)row * HH;
#pragma unroll
    for (int i = 0; i < 8; ++i) {
        float v = (x[i] - mean) * rs * g[lane + i * 64] + be[lane + i * 64];
        po[lane + i * 64] = v;
        if (BF16OUT) pob[lane + i * 64] = f2bf(v);
    }
}

extern "C" void kernel_launch(void* const* d_in, const int* in_sizes, int n_in,
                              void* d_out, int out_size, void* d_ws, size_t ws_size,
                              hipStream_t stream) {
    const float* x   = (const float*)d_in[0];
    const int*  eidx = (const int*)d_in[1];
    const float* ea  = (const float*)d_in[2];
    const float* Wn = (const float*)d_in[3];  const float* bn = (const float*)d_in[4];
    const float* We = (const float*)d_in[5];  const float* be = (const float*)d_in[6];
    const float* Wq = (const float*)d_in[7];  const float* bq = (const float*)d_in[8];
    const float* Wk = (const float*)d_in[9];  const float* bk = (const float*)d_in[10];
    const float* Wv = (const float*)d_in[11]; const float* bv = (const float*)d_in[12];
    const float* Wo = (const float*)d_in[13]; const float* bo = (const float*)d_in[14];
    const float* W1 = (const float*)d_in[15]; const float* b1 = (const float*)d_in[16];
    const float* W2 = (const float*)d_in[17]; const float* b2 = (const float*)d_in[18];
    const float* g1 = (const float*)d_in[19]; const float* be1 = (const float*)d_in[20];
    const float* g2 = (const float*)d_in[21]; const float* be2 = (const float*)d_in[22];
    float* out = (float*)d_out;

    // workspace carve (bytes, 256-aligned)
    char* base = (char*)d_ws;
    size_t off = 0;
    auto carve = [&](size_t bytes) { void* p = base + off; off = (off + bytes + 255) & ~(size_t)255; return p; };
    float*  h    = (float*)carve((size_t)NN * HH * 4);
    ushort* hb   = (ushort*)carve((size_t)NN * HH * 2);
    // [po, ff1b, qb, kbf] contiguous 16 MB -> aliased as lastE during setup
    float*  po   = (float*)carve((size_t)NN * HH * 4);
    ushort* ff1b = (ushort*)carve((size_t)NN * 4 * HH * 2);   // also opart (8 MB f32)
    ushort* qb   = (ushort*)carve((size_t)NN * HH * 2);
    ushort* kbf  = (ushort*)carve((size_t)NN * HH * 2);
    ushort* vtb  = (ushort*)carve((size_t)NN * HH * 2);
    ushort* aob  = (ushort*)carve((size_t)NN * HH * 2);
    ushort* xb   = (ushort*)carve((size_t)NN * NF_ * 2);
    ushort* WnT  = (ushort*)carve((size_t)HH * NF_ * 2);
    ushort* WqkvT= (ushort*)carve((size_t)3 * HH * HH * 2);
    ushort* WoT  = (ushort*)carve((size_t)HH * HH * 2);
    ushort* W1T  = (ushort*)carve((size_t)4 * HH * HH * 2);
    ushort* W2T  = (ushort*)carve((size_t)4 * HH * HH * 2);
    float*  bqkv = (float*)carve((size_t)3 * HH * 4);
    float*  eb   = (float*)carve((size_t)EE * NHH * 4);
    float*  csr_b= (float*)carve((size_t)EE * NHH * 4);
    float*  Mp   = (float*)carve((size_t)KSPLIT * NHH * NN * 4);
    float*  Sp   = (float*)carve((size_t)KSPLIT * NHH * NN * 4);
    int* cnt     = (int*)carve((size_t)NN * 4);
    int* rowptr  = (int*)carve((size_t)(NN + 1) * 4);
    int* csr_dst = (int*)carve((size_t)EE * 4);
    int* cnt2    = (int*)carve((size_t)NN * NTILE_TOT * 4);
    int* rtptr   = (int*)carve((size_t)(NN * NTILE_TOT + 1) * 4);
    int* rtoff   = (int*)carve((size_t)NN * NTILE_TOT * 4);
    int* lastE = (int*)po;            // setup alias (po+ff1b+qb+kbf = 16 MB)
    float* opart = (float*)ff1b;      // attention partials alias FF intermediate

    // ---- setup
    hipMemsetAsync(lastE, 0xFF, (size_t)NN * NN * 4, stream);
    hipMemsetAsync(cnt, 0, (size_t)NN * 4, stream);
    hipMemsetAsync(cnt2, 0, (size_t)NN * NTILE_TOT * 4, stream);

    xcvt<<<(NN * NF_ + 255) / 256, 256, 0, stream>>>(x, xb, NN * NF_);
    wtrans<<<dim3(HH / 32, NF_ / 32), 256, 0, stream>>>(Wn, WnT, NF_, HH, 0);
    wtrans<<<dim3(HH / 32, HH / 32), 256, 0, stream>>>(Wq, WqkvT, HH, HH, 0);
    wtrans<<<dim3(HH / 32, HH / 32), 256, 0, stream>>>(Wk, WqkvT, HH, HH, 512);
    wtrans<<<dim3(HH / 32, HH / 32), 256, 0, stream>>>(Wv, WqkvT, HH, HH, 1024);
    wtrans<<<dim3(HH / 32, HH / 32), 256, 0, stream>>>(Wo, WoT, HH, HH, 0);
    wtrans<<<dim3(4 * HH / 32, HH / 32), 256, 0, stream>>>(W1, W1T, HH, 4 * HH, 0);
    wtrans<<<dim3(HH / 32, 4 * HH / 32), 256, 0, stream>>>(W2, W2T, 4 * HH, HH, 0);
    bconcat<<<6, 256, 0, stream>>>(bq, bk, bv, bqkv);

    ebias_kernel<<<EE / 256, 256, 0, stream>>>(ea, We, be, eb);
    amax_kernel<<<EE / 256, 256, 0, stream>>>(eidx, lastE);
    count_kernel<<<EE / 256, 256, 0, stream>>>(eidx, lastE, cnt);
    scan2048<<<1, 256, 0, stream>>>(cnt, rowptr);
    rt_count<<<EE / 256, 256, 0, stream>>>(eidx, lastE, cnt2);
    rt_scan<<<NN / 256, 256, 0, stream>>>(rowptr, cnt2, rtptr, rtoff);
    rt_fill<<<EE / 256, 256, 0, stream>>>(eidx, lastE, eb, rtoff, csr_dst, csr_b);

    // h = x @ Wn + bn  (f32 + bf16)
    gemm_mfma<64, 1, 0><<<dim3(HH / 64, NN / 128), 256, 0, stream>>>(
        xb, WnT, bn, h, hb, nullptr, nullptr, nullptr, NN, HH, NF_);

    // ---- transformer layers
    for (int d = 0; d < DEPTH; ++d) {
        gemm_mfma<128, 3, 0><<<dim3(3 * HH / 128, NN / 128), 256, 0, stream>>>(
            hb, WqkvT, bqkv, nullptr, nullptr, qb, kbf, vtb, NN, 3 * HH, HH);
        attn_mfma<<<dim3(NN / 32, NHH, KSPLIT), 256, 0, stream>>>(
            qb, kbf, vtb, rtptr, csr_dst, csr_b, opart, Mp, Sp);
        attn_combine<<<NN * HH / 256, 256, 0, stream>>>(opart, Mp, Sp, aob);
        gemm_mfma<64, 0, 0><<<dim3(HH / 64, NN / 128), 256, 0, stream>>>(
            aob, WoT, bo, po, nullptr, nullptr, nullptr, nullptr, NN, HH, HH);
        ln_kernel<1><<<NN / 4, 256, 0, stream>>>(h, po, g1, be1, h, hb);
        gemm_mfma<128, 2, 1><<<dim3(4 * HH / 128, NN / 128), 256, 0, stream>>>(
            hb, W1T, b1, nullptr, ff1b, nullptr, nullptr, nullptr, NN, 4 * HH, HH);
        gemm_mfma<64, 0, 0><<<dim3(HH / 64, NN / 128), 256, 0, stream>>>(
            ff1b, W2T, b2, po, nullptr, nullptr, nullptr, nullptr, NN, HH, 4 * HH);
        float* dst = (d == DEPTH - 1) ? out : h;
        ln_kernel<1><<<NN / 4, 256, 0, stream>>>(h, po, g2, be2, dst, hb);
    }
    (void)in_sizes; (void)n_in; (void)out_size; (void)ws_size;
}

// Round 7
// 640.845 us; speedup vs baseline: 1.7845x; 1.1225x over previous
//
#include <hip/hip_runtime.h>
#include <hip/hip_bf16.h>

// Problem constants (fixed shapes)
#define NN 2048      // nodes
#define EE 65536     // edges
#define NF_ 128
#define HH 512
#define NHH 8
#define HD 64
#define DEPTH 5
#define KSPLIT 2
#define KEYS_PER (NN / KSPLIT)   // 1024
#define NTILE (KEYS_PER / 64)    // 16
#define NTILE_TOT (NN / 64)      // 32
#define LOG2E 1.4426950408889634f

typedef __attribute__((ext_vector_type(8))) short bf16x8;
typedef __attribute__((ext_vector_type(4))) float f32x4;

__device__ __forceinline__ ushort f2bf(float x) {
    uint u = __builtin_bit_cast(uint, x);
    u += 0x7fffu + ((u >> 16) & 1u);
    return (ushort)(u >> 16);
}

#define GLD16(gp, lp)                                                          \
    __builtin_amdgcn_global_load_lds(                                          \
        (const __attribute__((address_space(1))) unsigned int*)(gp),           \
        (__attribute__((address_space(3))) unsigned int*)(lp), 16, 0, 0)

// raw barrier: LDS visible, vmem loads stay in flight
__device__ __forceinline__ void bar_lgkm() {
    asm volatile("s_waitcnt lgkmcnt(0)" ::: "memory");
    __builtin_amdgcn_s_barrier();
    __builtin_amdgcn_sched_barrier(0);
}
__device__ __forceinline__ void bar_vm(int pk) {
    if (pk) asm volatile("s_waitcnt vmcnt(2) lgkmcnt(0)" ::: "memory");
    else    asm volatile("s_waitcnt vmcnt(0) lgkmcnt(0)" ::: "memory");
    __builtin_amdgcn_s_barrier();
    __builtin_amdgcn_sched_barrier(0);
}

// ---------------- bf16 MFMA GEMM: C = A[M,K] @ Bt[N,K]^T + bias
// BM x BN tile, BK=64, 4 waves (2x2); global_load_lds staging; T2 XOR swizzle both-sides.
// OUT: 0 = f32 C; 1 = f32 C + bf16 Cb; 2 = bf16 Cb; 3 = qkv scatter (q/k head-major, v transposed)
template<int BM, int BN, int OUT, int RELU>
__global__ __launch_bounds__(256) void gemm_mfma(const ushort* __restrict__ A,
                                                 const ushort* __restrict__ Bt,
                                                 const float* __restrict__ bias,
                                                 float* __restrict__ C,
                                                 ushort* __restrict__ Cb,
                                                 ushort* __restrict__ qb,
                                                 ushort* __restrict__ kb,
                                                 ushort* __restrict__ vtb,
                                                 int M, int N, int K) {
    constexpr int WM = BM / 2, WN = BN / 2;
    constexpr int MR = BM / 32, NR = BN / 32;
    __shared__ __align__(16) ushort As[2][BM * 64];
    __shared__ __align__(16) ushort Bs[2][BN * 64];
    const int t = threadIdx.x;
    const int w = t >> 6, l = t & 63;
    const int wr = w >> 1, wc = w & 1;
    const int m0 = blockIdx.y * BM, n0 = blockIdx.x * BN;

    f32x4 acc[MR][NR];
#pragma unroll
    for (int m = 0; m < MR; ++m)
#pragma unroll
        for (int n = 0; n < NR; ++n) acc[m][n] = (f32x4){0.f, 0.f, 0.f, 0.f};

    const int srow = t >> 3, sch = t & 7;
    auto stage = [&](int buf, int kt) {
#pragma unroll
        for (int r = 0; r < MR; ++r) {
            int rr = r * 32 + srow;
            int c = sch ^ (rr & 7);                   // inverse swizzle on SOURCE
            GLD16(A + (size_t)(m0 + rr) * K + kt * 64 + c * 8,
                  &As[buf][rr * 64 + sch * 8]);       // linear LDS dest
        }
#pragma unroll
        for (int r = 0; r < NR; ++r) {
            int rr = r * 32 + srow;
            int c = sch ^ (rr & 7);
            GLD16(Bt + (size_t)(n0 + rr) * K + kt * 64 + c * 8,
                  &Bs[buf][rr * 64 + sch * 8]);
        }
    };

    stage(0, 0);
    const int NT = K / 64;
    for (int kt = 0; kt < NT; ++kt) {
        __syncthreads();
        if (kt + 1 < NT) stage((kt + 1) & 1, kt + 1);
        const int buf = kt & 1;
#pragma unroll
        for (int kk = 0; kk < 2; ++kk) {
            bf16x8 af[MR], bfr[NR];
#pragma unroll
            for (int m = 0; m < MR; ++m) {
                int R = wr * WM + m * 16 + (l & 15);
                int c = kk * 4 + (l >> 4);
                af[m] = *(const bf16x8*)&As[buf][R * 64 + (c ^ (R & 7)) * 8];  // swizzled read
            }
#pragma unroll
            for (int n = 0; n < NR; ++n) {
                int R = wc * WN + n * 16 + (l & 15);
                int c = kk * 4 + (l >> 4);
                bfr[n] = *(const bf16x8*)&Bs[buf][R * 64 + (c ^ (R & 7)) * 8];
            }
#pragma unroll
            for (int m = 0; m < MR; ++m)
#pragma unroll
                for (int n = 0; n < NR; ++n)
                    acc[m][n] = __builtin_amdgcn_mfma_f32_16x16x32_bf16(af[m], bfr[n], acc[m][n], 0, 0, 0);
        }
    }

    // epilogue: C/D layout col=l&15, row=(l>>4)*4+j
#pragma unroll
    for (int m = 0; m < MR; ++m) {
        int row = m0 + wr * WM + m * 16 + (l >> 4) * 4;
#pragma unroll
        for (int n = 0; n < NR; ++n) {
            int col = n0 + wc * WN + n * 16 + (l & 15);
            float bv = bias[col];
#pragma unroll
            for (int j = 0; j < 4; ++j) {
                float vv = acc[m][n][j] + bv;
                if (RELU) vv = fmaxf(vv, 0.f);
                int r = row + j;
                if (OUT == 0) {
                    C[(size_t)r * N + col] = vv;
                } else if (OUT == 1) {
                    C[(size_t)r * N + col] = vv;
                    Cb[(size_t)r * N + col] = f2bf(vv);
                } else if (OUT == 2) {
                    Cb[(size_t)r * N + col] = f2bf(vv);
                } else {
                    int type = col >> 9, head = (col >> 6) & 7, dd = col & 63;
                    ushort bv16 = f2bf(vv);
                    if (type == 0) qb[((size_t)head * NN + r) * 64 + dd] = bv16;
                    else if (type == 1) kb[((size_t)head * NN + r) * 64 + dd] = bv16;
                    else vtb[((size_t)head * 64 + dd) * NN + r] = bv16;
                }
            }
        }
    }
}

// ---------------- setup converts
__global__ __launch_bounds__(256) void xcvt(const float* __restrict__ x, ushort* __restrict__ xb, int n) {
    int i = blockIdx.x * 256 + threadIdx.x;
    if (i < n) xb[i] = f2bf(x[i]);
}

__global__ __launch_bounds__(256) void wtrans(const float* __restrict__ W, ushort* __restrict__ WT,
                                              int K, int N, int rowoff) {
    __shared__ float tile[32][33];
    int n0 = blockIdx.x * 32, k0 = blockIdx.y * 32;
    int tc = threadIdx.x & 31, tr = threadIdx.x >> 5;
#pragma unroll
    for (int i = 0; i < 32; i += 8) tile[tr + i][tc] = W[(size_t)(k0 + tr + i) * N + n0 + tc];
    __syncthreads();
#pragma unroll
    for (int i = 0; i < 32; i += 8)
        WT[(size_t)(rowoff + n0 + tr + i) * K + k0 + tc] = f2bf(tile[tc][tr + i]);
}

__global__ __launch_bounds__(256) void bconcat(const float* __restrict__ a, const float* __restrict__ b,
                                               const float* __restrict__ c, float* __restrict__ o) {
    int i = blockIdx.x * 256 + threadIdx.x;
    if (i < 1536) o[i] = i < 512 ? a[i] : (i < 1024 ? b[i - 512] : c[i - 1024]);
}

// ---------------- e_bias = edge_attr @ We + be
__global__ __launch_bounds__(256) void ebias_kernel(const float* __restrict__ ea,
                                                    const float* __restrict__ We,
                                                    const float* __restrict__ be,
                                                    float* __restrict__ eb) {
    int e = blockIdx.x * 256 + threadIdx.x;
    float a[16];
#pragma unroll
    for (int i = 0; i < 16; ++i) a[i] = ea[(size_t)e * 16 + i];
#pragma unroll
    for (int j = 0; j < 8; ++j) {
        float s = be[j];
#pragma unroll
        for (int i = 0; i < 16; ++i) s += a[i] * We[i * 8 + j];
        eb[(size_t)e * 8 + j] = s;
    }
}

// ---------------- dedupe: last edge index wins per (src,dst)
__global__ __launch_bounds__(256) void amax_kernel(const int* __restrict__ eidx, int* __restrict__ lastE) {
    int e = blockIdx.x * 256 + threadIdx.x;
    int s = eidx[e], d = eidx[EE + e];
    atomicMax(&lastE[s * NN + d], e);
}

__global__ __launch_bounds__(256) void count_kernel(const int* __restrict__ eidx,
                                                    const int* __restrict__ lastE,
                                                    int* __restrict__ cnt) {
    int e = blockIdx.x * 256 + threadIdx.x;
    int s = eidx[e], d = eidx[EE + e];
    if (lastE[s * NN + d] == e) atomicAdd(&cnt[s], 1);
}

__global__ __launch_bounds__(256) void scan2048(const int* __restrict__ cnt,
                                                int* __restrict__ rowptr) {
    __shared__ int sums[256];
    int t = threadIdx.x;
    int loc[8];
    int s = 0;
#pragma unroll
    for (int i = 0; i < 8; ++i) { loc[i] = s; s += cnt[t * 8 + i]; }
    sums[t] = s;
    __syncthreads();
    for (int off = 1; off < 256; off <<= 1) {
        int v = (t >= off) ? sums[t - off] : 0;
        __syncthreads();
        sums[t] += v;
        __syncthreads();
    }
    int base = (t == 0) ? 0 : sums[t - 1];
#pragma unroll
    for (int i = 0; i < 8; ++i) rowptr[t * 8 + i] = base + loc[i];
    if (t == 255) rowptr[NN] = sums[255];
}

// ---------------- (row, key-tile) bucketing of bias entries (layer-invariant)
__global__ __launch_bounds__(256) void rt_count(const int* __restrict__ eidx,
                                                const int* __restrict__ lastE,
                                                int* __restrict__ cnt2) {
    int e = blockIdx.x * 256 + threadIdx.x;
    int s = eidx[e], d = eidx[EE + e];
    if (lastE[s * NN + d] == e) atomicAdd(&cnt2[s * NTILE_TOT + (d >> 6)], 1);
}

__global__ __launch_bounds__(256) void rt_scan(const int* __restrict__ rowptr,
                                               const int* __restrict__ cnt2,
                                               int* __restrict__ rtptr,
                                               int* __restrict__ rtoff) {
    int row = blockIdx.x * 256 + threadIdx.x;
    if (row >= NN) return;
    int base = rowptr[row];
#pragma unroll
    for (int t = 0; t < NTILE_TOT; ++t) {
        rtptr[row * NTILE_TOT + t] = base;
        rtoff[row * NTILE_TOT + t] = base;
        base += cnt2[row * NTILE_TOT + t];
    }
    if (row == NN - 1) rtptr[NN * NTILE_TOT] = base;
}

// fill buckets: dst stored relative to tile (0..63); bias pre-scaled by log2e
__global__ __launch_bounds__(256) void rt_fill(const int* __restrict__ eidx,
                                               const int* __restrict__ lastE,
                                               const float* __restrict__ eb,
                                               int* __restrict__ rtoff,
                                               int* __restrict__ csr_dst,
                                               float* __restrict__ csr_b) {
    int e = blockIdx.x * 256 + threadIdx.x;
    int s = eidx[e], d = eidx[EE + e];
    if (lastE[s * NN + d] == e) {
        int pos = atomicAdd(&rtoff[s * NTILE_TOT + (d >> 6)], 1);
        csr_dst[pos] = d & 63;
#pragma unroll
        for (int j = 0; j < 8; ++j) csr_b[(size_t)pos * 8 + j] = eb[(size_t)e * 8 + j] * LOG2E;
    }
}

// ---------------- split-K flash attention with MFMA bf16 (log2-space softmax)
// flat grid 1024 = qblk(64) x head(8) x ks(2), XCD-chunk swizzled.
__global__ __launch_bounds__(256) void attn_mfma(const ushort* __restrict__ qb,
                                                 const ushort* __restrict__ kb,
                                                 const ushort* __restrict__ vtb,
                                                 const int* __restrict__ rtptr,
                                                 const int* __restrict__ csr_dst,
                                                 const float* __restrict__ csr_b,
                                                 float* __restrict__ opart,
                                                 float* __restrict__ Mp,
                                                 float* __restrict__ Sp) {
    // XCD-aware swizzle: 1024 blocks, 8 XCDs -> chunks of 128 per XCD
    const int id = blockIdx.x;
    const int f = (id & 7) * 128 + (id >> 3);
    const int n0 = (f & 63) * 32;
    const int head = (f >> 6) & 7;
    const int ks = f >> 9;
    const int t = threadIdx.x;
    const int w = t >> 6, l = t & 63;
    const int mh = w & 1, nh = w >> 1;
    const float c1 = 0.125f * LOG2E;   // qk scale in log2 space

    __shared__ __align__(16) ushort Ks2[2][64 * 64];   // K dbuf, swizzled
    __shared__ __align__(16) ushort Vs[64 * 64];       // V single buf, swizzled
    __shared__ __align__(16) float  Sl[32][68];
    __shared__ __align__(16) ushort Pb[32][72];
    __shared__ float Mrow[32], Srow[32], Frow[32];
    __shared__ int Rt[32][17];                          // bucket boundaries for this block

    bf16x8 qf0, qf1;
    {
        int r = n0 + mh * 16 + (l & 15);
        const ushort* qp = qb + ((size_t)head * NN + r) * HD + ((l >> 4) * 8);
        qf0 = *(const bf16x8*)qp;
        qf1 = *(const bf16x8*)(qp + 32);
    }
    if (t < 32) { Mrow[t] = -1e30f; Srow[t] = 0.f; }
    for (int i = t; i < 32 * 17; i += 256) {
        int r = i / 17, c = i % 17;
        Rt[r][c] = rtptr[(n0 + r) * NTILE_TOT + ks * NTILE + c];
    }
    const int brow = t >> 3, bj = t & 7;
    f32x4 o0 = {0.f, 0.f, 0.f, 0.f}, o1 = {0.f, 0.f, 0.f, 0.f};

    auto stageK = [&](int buf, int tile) {
        int m0k = ks * KEYS_PER + tile * 64;
#pragma unroll
        for (int s = 0; s < 2; ++s) {
            int slot = t + s * 256;
            int rr = slot >> 3, blk = slot & 7, sb = blk ^ (rr & 7);
            GLD16(kb + ((size_t)head * NN + m0k + rr) * 64 + sb * 8,
                  &Ks2[buf][rr * 64 + blk * 8]);
        }
    };
    auto stageV = [&](int tile) {
        int m0k = ks * KEYS_PER + tile * 64;
#pragma unroll
        for (int s = 0; s < 2; ++s) {
            int slot = t + s * 256;
            int rr = slot >> 3, blk = slot & 7, sb = blk ^ (rr & 7);
            GLD16(vtb + ((size_t)head * 64 + rr) * NN + m0k + sb * 8,
                  &Vs[rr * 64 + blk * 8]);
        }
    };

    stageK(0, 0);
    __syncthreads();   // K(0) landed, Mrow/Rt visible

    for (int tt = 0; tt < NTILE; ++tt) {
        const int buf = tt & 1;
        const int pk = (tt + 1 < NTILE);
        stageV(tt);
        if (pk) stageK(buf ^ 1, tt + 1);

        // ---- QK^T from Ks2[buf] (swizzled reads)
        {
            const ushort* Kb_ = &Ks2[buf][0];
            int db = l >> 4;
            int key0 = nh * 32 + (l & 15), key1 = key0 + 16;
            bf16x8 ka0 = *(const bf16x8*)&Kb_[key0 * 64 + ((db ^ (key0 & 7)) * 8)];
            bf16x8 ka1 = *(const bf16x8*)&Kb_[key0 * 64 + (((db + 4) ^ (key0 & 7)) * 8)];
            bf16x8 kb0 = *(const bf16x8*)&Kb_[key1 * 64 + ((db ^ (key1 & 7)) * 8)];
            bf16x8 kb1 = *(const bf16x8*)&Kb_[key1 * 64 + (((db + 4) ^ (key1 & 7)) * 8)];
            f32x4 s0 = {0.f, 0.f, 0.f, 0.f}, s1 = {0.f, 0.f, 0.f, 0.f};
            __builtin_amdgcn_s_setprio(1);
            s0 = __builtin_amdgcn_mfma_f32_16x16x32_bf16(qf0, ka0, s0, 0, 0, 0);
            s0 = __builtin_amdgcn_mfma_f32_16x16x32_bf16(qf1, ka1, s0, 0, 0, 0);
            s1 = __builtin_amdgcn_mfma_f32_16x16x32_bf16(qf0, kb0, s1, 0, 0, 0);
            s1 = __builtin_amdgcn_mfma_f32_16x16x32_bf16(qf1, kb1, s1, 0, 0, 0);
            __builtin_amdgcn_s_setprio(0);
            int row = mh * 16 + (l >> 4) * 4;
            int c0 = nh * 32 + (l & 15);
#pragma unroll
            for (int j = 0; j < 4; ++j) {
                Sl[row + j][c0] = s0[j] * c1;
                Sl[row + j][c0 + 16] = s1[j] * c1;
            }
        }
        bar_lgkm();   // Sl visible; staging loads stay in flight

        // ---- bias (pre-bucketed, ~1 entry/row/tile) + online softmax (log2 space)
        {
            const int cbase = bj * 8;
            const int p0 = Rt[brow][tt], p1 = Rt[brow][tt + 1];
            for (int e = p0; e < p1; ++e) {
                int dd = csr_dst[e];                 // 0..63 within tile
                if ((dd >> 3) == bj) Sl[brow][dd] += csr_b[(size_t)e * 8 + head];
            }
            f32x4 a = *(const f32x4*)&Sl[brow][cbase];
            f32x4 b = *(const f32x4*)&Sl[brow][cbase + 4];
            float tm = fmaxf(fmaxf(fmaxf(a[0], a[1]), fmaxf(a[2], a[3])),
                             fmaxf(fmaxf(b[0], b[1]), fmaxf(b[2], b[3])));
            tm = fmaxf(tm, __shfl_xor(tm, 1, 64));
            tm = fmaxf(tm, __shfl_xor(tm, 2, 64));
            tm = fmaxf(tm, __shfl_xor(tm, 4, 64));
            float Mo = Mrow[brow];
            float Mn = fmaxf(Mo, tm);
            float p[8];
#pragma unroll
            for (int i = 0; i < 4; ++i) p[i] = exp2f(a[i] - Mn);
#pragma unroll
            for (int i = 0; i < 4; ++i) p[4 + i] = exp2f(b[i] - Mn);
            float ts = 0.f;
#pragma unroll
            for (int i = 0; i < 8; ++i) ts += p[i];
            ts += __shfl_xor(ts, 1, 64);
            ts += __shfl_xor(ts, 2, 64);
            ts += __shfl_xor(ts, 4, 64);
            int4 pkv;
            pkv.x = (int)((uint)f2bf(p[0]) | ((uint)f2bf(p[1]) << 16));
            pkv.y = (int)((uint)f2bf(p[2]) | ((uint)f2bf(p[3]) << 16));
            pkv.z = (int)((uint)f2bf(p[4]) | ((uint)f2bf(p[5]) << 16));
            pkv.w = (int)((uint)f2bf(p[6]) | ((uint)f2bf(p[7]) << 16));
            *(int4*)&Pb[brow][cbase] = pkv;
            if (bj == 0) {
                float f_ = exp2f(Mo - Mn);
                Mrow[brow] = Mn;
                Srow[brow] = Srow[brow] * f_ + ts;
                Frow[brow] = f_;
            }
        }
        bar_vm(pk);   // Pb/Frow visible AND V landed (K prefetch may stay in flight)

        // ---- rescale + PV (swizzled V reads)
        {
            int row4 = mh * 16 + (l >> 4) * 4;
#pragma unroll
            for (int j = 0; j < 4; ++j) {
                float fj = Frow[row4 + j];
                o0[j] *= fj;
                o1[j] *= fj;
            }
            int kbase = (l >> 4) * 8;
            int prow = mh * 16 + (l & 15);
            bf16x8 p0 = *(const bf16x8*)&Pb[prow][kbase];
            bf16x8 p1 = *(const bf16x8*)&Pb[prow][kbase + 32];
            int kb_ = l >> 4;
            int d0 = nh * 32 + (l & 15), d1 = d0 + 16;
            bf16x8 v00 = *(const bf16x8*)&Vs[d0 * 64 + ((kb_ ^ (d0 & 7)) * 8)];
            bf16x8 v01 = *(const bf16x8*)&Vs[d0 * 64 + (((kb_ + 4) ^ (d0 & 7)) * 8)];
            bf16x8 v10 = *(const bf16x8*)&Vs[d1 * 64 + ((kb_ ^ (d1 & 7)) * 8)];
            bf16x8 v11 = *(const bf16x8*)&Vs[d1 * 64 + (((kb_ + 4) ^ (d1 & 7)) * 8)];
            __builtin_amdgcn_s_setprio(1);
            o0 = __builtin_amdgcn_mfma_f32_16x16x32_bf16(p0, v00, o0, 0, 0, 0);
            o0 = __builtin_amdgcn_mfma_f32_16x16x32_bf16(p1, v01, o0, 0, 0, 0);
            o1 = __builtin_amdgcn_mfma_f32_16x16x32_bf16(p0, v10, o1, 0, 0, 0);
            o1 = __builtin_amdgcn_mfma_f32_16x16x32_bf16(p1, v11, o1, 0, 0, 0);
            __builtin_amdgcn_s_setprio(0);
        }
        __syncthreads();
    }

    // ---- write partials (unnormalized o, plus M,S; M in log2 units)
    {
        int row4 = mh * 16 + (l >> 4) * 4;
        int c0 = nh * 32 + (l & 15);
#pragma unroll
        for (int j = 0; j < 4; ++j) {
            int r = row4 + j;
            float* dst = opart + ((size_t)ks * NN + n0 + r) * HH + head * HD;
            dst[c0] = o0[j];
            dst[c0 + 16] = o1[j];
        }
    }
    if (t < 32) {
        Mp[((size_t)ks * NHH + head) * NN + n0 + t] = Mrow[t];
        Sp[((size_t)ks * NHH + head) * NN + n0 + t] = Srow[t];
    }
}

// combine 2 partials -> bf16 attention output (log2-space M)
__global__ __launch_bounds__(256) void attn_combine(const float* __restrict__ opart,
                                                    const float* __restrict__ Mp,
                                                    const float* __restrict__ Sp,
                                                    ushort* __restrict__ aob) {
    int i = blockIdx.x * 256 + threadIdx.x;
    int row = i >> 9, col = i & 511;
    int head = col >> 6;
    float m0 = Mp[(size_t)head * NN + row];
    float m1 = Mp[((size_t)NHH + head) * NN + row];
    float s0 = Sp[(size_t)head * NN + row];
    float s1 = Sp[((size_t)NHH + head) * NN + row];
    float m = fmaxf(m0, m1);
    float w0 = exp2f(m0 - m), w1 = exp2f(m1 - m);
    float ov0 = opart[(size_t)row * HH + col];
    float ov1 = opart[((size_t)NN + row) * HH + col];
    aob[i] = f2bf((ov0 * w0 + ov1 * w1) / (s0 * w0 + s1 * w1));
}

// ---------------- LayerNorm(out = LN(a + b) * g + be); optional bf16 copy
template<int BF16OUT>
__global__ __launch_bounds__(256) void ln_kernel(const float* __restrict__ a,
                                                 const float* __restrict__ b,
                                                 const float* __restrict__ g,
                                                 const float* __restrict__ be,
                                                 float* __restrict__ out,
                                                 ushort* __restrict__ outb) {
    int row = blockIdx.x * 4 + (threadIdx.x >> 6);
    int lane = threadIdx.x & 63;
    const float* pa = a + (size_t)row * HH;
    const float* pb = b + (size_t)row * HH;
    float x[8];
    float s = 0.f;
#pragma unroll
    for (int i = 0; i < 8; ++i) { x[i] = pa[lane + i * 64] + pb[lane + i * 64]; s += x[i]; }
#pragma unroll
    for (int off = 32; off > 0; off >>= 1) s += __shfl_xor(s, off, 64);
    float mean = s * (1.f / 512.f);
    float vs = 0.f;
#pragma unroll
    for (int i = 0; i < 8; ++i) { float d = x[i] - mean; vs += d * d; }
#pragma unroll
    for (int off = 32; off > 0; off >>= 1) vs += __shfl_xor(vs, off, 64);
    float rs = rsqrtf(vs * (1.f / 512.f) + 1e-5f);
    float* po = out + (size_t)row * HH;
    ushort* pob = outb + (size_t)row * HH;
#pragma unroll
    for (int i = 0; i < 8; ++i) {
        float v = (x[i] - mean) * rs * g[lane + i * 64] + be[lane + i * 64];
        po[lane + i * 64] = v;
        if (BF16OUT) pob[lane + i * 64] = f2bf(v);
    }
}

extern "C" void kernel_launch(void* const* d_in, const int* in_sizes, int n_in,
                              void* d_out, int out_size, void* d_ws, size_t ws_size,
                              hipStream_t stream) {
    const float* x   = (const float*)d_in[0];
    const int*  eidx = (const int*)d_in[1];
    const float* ea  = (const float*)d_in[2];
    const float* Wn = (const float*)d_in[3];  const float* bn = (const float*)d_in[4];
    const float* We = (const float*)d_in[5];  const float* be = (const float*)d_in[6];
    const float* Wq = (const float*)d_in[7];  const float* bq = (const float*)d_in[8];
    const float* Wk = (const float*)d_in[9];  const float* bk = (const float*)d_in[10];
    const float* Wv = (const float*)d_in[11]; const float* bv = (const float*)d_in[12];
    const float* Wo = (const float*)d_in[13]; const float* bo = (const float*)d_in[14];
    const float* W1 = (const float*)d_in[15]; const float* b1 = (const float*)d_in[16];
    const float* W2 = (const float*)d_in[17]; const float* b2 = (const float*)d_in[18];
    const float* g1 = (const float*)d_in[19]; const float* be1 = (const float*)d_in[20];
    const float* g2 = (const float*)d_in[21]; const float* be2 = (const float*)d_in[22];
    float* out = (float*)d_out;

    // workspace carve (bytes, 256-aligned)
    char* base = (char*)d_ws;
    size_t off = 0;
    auto carve = [&](size_t bytes) { void* p = base + off; off = (off + bytes + 255) & ~(size_t)255; return p; };
    float*  h    = (float*)carve((size_t)NN * HH * 4);
    ushort* hb   = (ushort*)carve((size_t)NN * HH * 2);
    // [po, ff1b, qb, kbf] contiguous 16 MB -> aliased as lastE during setup
    float*  po   = (float*)carve((size_t)NN * HH * 4);
    ushort* ff1b = (ushort*)carve((size_t)NN * 4 * HH * 2);   // also opart (8 MB f32)
    ushort* qb   = (ushort*)carve((size_t)NN * HH * 2);
    ushort* kbf  = (ushort*)carve((size_t)NN * HH * 2);
    ushort* vtb  = (ushort*)carve((size_t)NN * HH * 2);
    ushort* aob  = (ushort*)carve((size_t)NN * HH * 2);
    ushort* xb   = (ushort*)carve((size_t)NN * NF_ * 2);
    ushort* WnT  = (ushort*)carve((size_t)HH * NF_ * 2);
    ushort* WqkvT= (ushort*)carve((size_t)3 * HH * HH * 2);
    ushort* WoT  = (ushort*)carve((size_t)HH * HH * 2);
    ushort* W1T  = (ushort*)carve((size_t)4 * HH * HH * 2);
    ushort* W2T  = (ushort*)carve((size_t)4 * HH * HH * 2);
    float*  bqkv = (float*)carve((size_t)3 * HH * 4);
    float*  eb   = (float*)carve((size_t)EE * NHH * 4);
    float*  csr_b= (float*)carve((size_t)EE * NHH * 4);
    float*  Mp   = (float*)carve((size_t)KSPLIT * NHH * NN * 4);
    float*  Sp   = (float*)carve((size_t)KSPLIT * NHH * NN * 4);
    int* cnt     = (int*)carve((size_t)NN * 4);
    int* rowptr  = (int*)carve((size_t)(NN + 1) * 4);
    int* csr_dst = (int*)carve((size_t)EE * 4);
    int* cnt2    = (int*)carve((size_t)NN * NTILE_TOT * 4);
    int* rtptr   = (int*)carve((size_t)(NN * NTILE_TOT + 1) * 4);
    int* rtoff   = (int*)carve((size_t)NN * NTILE_TOT * 4);
    int* lastE = (int*)po;            // setup alias (po+ff1b+qb+kbf = 16 MB)
    float* opart = (float*)ff1b;      // attention partials alias FF intermediate

    // ---- setup
    hipMemsetAsync(lastE, 0xFF, (size_t)NN * NN * 4, stream);
    hipMemsetAsync(cnt, 0, (size_t)NN * 4, stream);
    hipMemsetAsync(cnt2, 0, (size_t)NN * NTILE_TOT * 4, stream);

    xcvt<<<(NN * NF_ + 255) / 256, 256, 0, stream>>>(x, xb, NN * NF_);
    wtrans<<<dim3(HH / 32, NF_ / 32), 256, 0, stream>>>(Wn, WnT, NF_, HH, 0);
    wtrans<<<dim3(HH / 32, HH / 32), 256, 0, stream>>>(Wq, WqkvT, HH, HH, 0);
    wtrans<<<dim3(HH / 32, HH / 32), 256, 0, stream>>>(Wk, WqkvT, HH, HH, 512);
    wtrans<<<dim3(HH / 32, HH / 32), 256, 0, stream>>>(Wv, WqkvT, HH, HH, 1024);
    wtrans<<<dim3(HH / 32, HH / 32), 256, 0, stream>>>(Wo, WoT, HH, HH, 0);
    wtrans<<<dim3(4 * HH / 32, HH / 32), 256, 0, stream>>>(W1, W1T, HH, 4 * HH, 0);
    wtrans<<<dim3(HH / 32, 4 * HH / 32), 256, 0, stream>>>(W2, W2T, 4 * HH, HH, 0);
    bconcat<<<6, 256, 0, stream>>>(bq, bk, bv, bqkv);

    ebias_kernel<<<EE / 256, 256, 0, stream>>>(ea, We, be, eb);
    amax_kernel<<<EE / 256, 256, 0, stream>>>(eidx, lastE);
    count_kernel<<<EE / 256, 256, 0, stream>>>(eidx, lastE, cnt);
    scan2048<<<1, 256, 0, stream>>>(cnt, rowptr);
    rt_count<<<EE / 256, 256, 0, stream>>>(eidx, lastE, cnt2);
    rt_scan<<<NN / 256, 256, 0, stream>>>(rowptr, cnt2, rtptr, rtoff);
    rt_fill<<<EE / 256, 256, 0, stream>>>(eidx, lastE, eb, rtoff, csr_dst, csr_b);

    // h = x @ Wn + bn  (f32 + bf16)
    gemm_mfma<64, 64, 1, 0><<<dim3(HH / 64, NN / 64), 256, 0, stream>>>(
        xb, WnT, bn, h, hb, nullptr, nullptr, nullptr, NN, HH, NF_);

    // ---- transformer layers
    for (int d = 0; d < DEPTH; ++d) {
        gemm_mfma<128, 64, 3, 0><<<dim3(3 * HH / 64, NN / 128), 256, 0, stream>>>(
            hb, WqkvT, bqkv, nullptr, nullptr, qb, kbf, vtb, NN, 3 * HH, HH);
        attn_mfma<<<dim3(1024), 256, 0, stream>>>(
            qb, kbf, vtb, rtptr, csr_dst, csr_b, opart, Mp, Sp);
        attn_combine<<<NN * HH / 256, 256, 0, stream>>>(opart, Mp, Sp, aob);
        gemm_mfma<32, 64, 0, 0><<<dim3(HH / 64, NN / 32), 256, 0, stream>>>(
            aob, WoT, bo, po, nullptr, nullptr, nullptr, nullptr, NN, HH, HH);
        ln_kernel<1><<<NN / 4, 256, 0, stream>>>(h, po, g1, be1, h, hb);
        gemm_mfma<128, 64, 2, 1><<<dim3(4 * HH / 64, NN / 128), 256, 0, stream>>>(
            hb, W1T, b1, nullptr, ff1b, nullptr, nullptr, nullptr, NN, 4 * HH, HH);
        gemm_mfma<32, 64, 0, 0><<<dim3(HH / 64, NN / 32), 256, 0, stream>>>(
            ff1b, W2T, b2, po, nullptr, nullptr, nullptr, nullptr, NN, HH, 4 * HH);
        float* dst = (d == DEPTH - 1) ? out : h;
        ln_kernel<1><<<NN / 4, 256, 0, stream>>>(h, po, g2, be2, dst, hb);
    }
    (void)in_sizes; (void)n_in; (void)out_size; (void)ws_size;
}